// Round 1
// baseline (2167.547 us; speedup 1.0000x reference)
//
#include <hip/hip_runtime.h>
#include <math.h>

// Sizes: B=4, N=1024, C=768, H=12, D=64
// ws layout (floats): q,k,v,qgr,kgr [48][1024][64] each; qn2,kn2 [48][1024]; attno [4096][768]

// ---------------- K1: qkv = x @ qkv_w^T + b, scatter to q,k,v [(b,h)][n][d] ----------------
__global__ __launch_bounds__(256) void qkv_gemm(
    const float* __restrict__ x, const float* __restrict__ w, const float* __restrict__ bias,
    float* __restrict__ q, float* __restrict__ k, float* __restrict__ v)
{
    __shared__ float As[16][68];
    __shared__ float Ws[16][68];
    const int tid = threadIdx.x;
    const int m0 = blockIdx.x * 64;
    const int c0 = blockIdx.y * 64;
    const int ty = tid >> 4, tx = tid & 15;
    const int lm = tid >> 2;
    const int lk = (tid & 3) * 4;
    float acc[4][4];
#pragma unroll
    for (int i = 0; i < 4; i++)
#pragma unroll
        for (int j = 0; j < 4; j++) acc[i][j] = 0.f;

    for (int kk0 = 0; kk0 < 768; kk0 += 16) {
        float4 av = *(const float4*)&x[(m0 + lm) * 768 + kk0 + lk];
        float4 wv = *(const float4*)&w[(c0 + lm) * 768 + kk0 + lk];
        __syncthreads();
        As[lk + 0][lm] = av.x; As[lk + 1][lm] = av.y; As[lk + 2][lm] = av.z; As[lk + 3][lm] = av.w;
        Ws[lk + 0][lm] = wv.x; Ws[lk + 1][lm] = wv.y; Ws[lk + 2][lm] = wv.z; Ws[lk + 3][lm] = wv.w;
        __syncthreads();
#pragma unroll
        for (int kk = 0; kk < 16; kk++) {
            float4 a  = *(const float4*)&As[kk][ty * 4];
            float4 bv = *(const float4*)&Ws[kk][tx * 4];
            acc[0][0] += a.x * bv.x; acc[0][1] += a.x * bv.y; acc[0][2] += a.x * bv.z; acc[0][3] += a.x * bv.w;
            acc[1][0] += a.y * bv.x; acc[1][1] += a.y * bv.y; acc[1][2] += a.y * bv.z; acc[1][3] += a.y * bv.w;
            acc[2][0] += a.z * bv.x; acc[2][1] += a.z * bv.y; acc[2][2] += a.z * bv.z; acc[2][3] += a.z * bv.w;
            acc[3][0] += a.w * bv.x; acc[3][1] += a.w * bv.y; acc[3][2] += a.w * bv.z; acc[3][3] += a.w * bv.w;
        }
    }
#pragma unroll
    for (int i = 0; i < 4; i++) {
        int row = m0 + ty * 4 + i;
        int bb = row >> 10, n = row & 1023;
#pragma unroll
        for (int j = 0; j < 4; j++) {
            int col = c0 + tx * 4 + j;
            float val = acc[i][j] + bias[col];
            int s = (col >= 1536) ? 2 : ((col >= 768) ? 1 : 0);
            int hc = col - s * 768;
            float* dst = (s == 0) ? q : ((s == 1) ? k : v);
            dst[((bb * 12 + (hc >> 6)) << 16) + (n << 6) + (hc & 63)] = val;
        }
    }
}

// ---------------- K1b: row norms |q_i|^2, |k_i|^2 ----------------
__global__ __launch_bounds__(256) void row_norms(
    const float* __restrict__ q, const float* __restrict__ k,
    float* __restrict__ qn2, float* __restrict__ kn2)
{
    int wid = blockIdx.x * 4 + (threadIdx.x >> 6);
    int lane = threadIdx.x & 63;
    const float* src; float* dst; int r;
    if (wid < 49152) { src = q; dst = qn2; r = wid; }
    else             { src = k; dst = kn2; r = wid - 49152; }
    float xv = src[r * 64 + lane];
    float s = xv * xv;
#pragma unroll
    for (int m = 1; m < 64; m <<= 1) s += __shfl_xor(s, m, 64);
    if (lane == 0) dst[r] = s;
}

// ---------------- K2: Householder QR (LAPACK sign convention), Q of [1024x64] ----------------
// One block (1024 thr = 16 waves) per (b,h,{q|k}). Wave w owns cols 4w..4w+3,
// lane holds rows lane, 64+lane, ..., 960+lane (16 regs per column).
__global__ __launch_bounds__(1024) void qr_kernel(
    const float* __restrict__ q, const float* __restrict__ k,
    float* __restrict__ qgr, float* __restrict__ kgr)
{
    const int id = blockIdx.x;
    const float* src = (id & 1) ? k : q;
    float* dst = (id & 1) ? kgr : qgr;
    const int bh = id >> 1;
    src += (size_t)bh << 16;
    dst += (size_t)bh << 16;
    const int lane = threadIdx.x & 63;
    const int w = threadIdx.x >> 6;
    __shared__ float vbuf[1024];
    __shared__ float taub[64];

    float a[4][16];
#pragma unroll
    for (int c = 0; c < 4; c++)
#pragma unroll
        for (int i = 0; i < 16; i++)
            a[c][i] = src[(i * 64 + lane) * 64 + 4 * w + c];

    // Phase 1: factorization. Reflector d: v stored in column d regs (pivot vd at row d), tau2 in LDS.
    for (int d = 0; d < 64; d++) {
        const int wd = d >> 2, cd = d & 3;
        if (w == wd) {
#pragma unroll
            for (int c = 0; c < 4; c++) if (c == cd) {
                float part = 0.f;
#pragma unroll
                for (int i = 0; i < 16; i++) {
                    int r = i * 64 + lane; float xx = a[c][i];
                    part += (r >= d) ? xx * xx : 0.f;
                }
#pragma unroll
                for (int m = 1; m < 64; m <<= 1) part += __shfl_xor(part, m, 64);
                float sigma = part;
                float xd = __shfl(a[c][0], d, 64);
                float nrm = sqrtf(sigma);
                float beta = (xd >= 0.f) ? -nrm : nrm;   // LAPACK: beta = -sign(xd)*||x||
                float vd = xd - beta;
                float vtv = (sigma - xd * xd) + vd * vd;
                float tau2 = (vtv > 0.f) ? 2.f / vtv : 0.f;
                if (lane == d) a[c][0] = vd;
#pragma unroll
                for (int i = 0; i < 16; i++) {
                    int r = i * 64 + lane;
                    vbuf[r] = (r < d) ? 0.f : a[c][i];
                }
                if (lane == 0) taub[d] = tau2;
            }
        }
        __syncthreads();
        float t2 = taub[d];
#pragma unroll
        for (int c = 0; c < 4; c++) {
            int j = 4 * w + c;
            if (j > d) {
                float part = 0.f;
#pragma unroll
                for (int i = 0; i < 16; i++) part += vbuf[i * 64 + lane] * a[c][i];
#pragma unroll
                for (int m = 1; m < 64; m <<= 1) part += __shfl_xor(part, m, 64);
                float sv = t2 * part;
#pragma unroll
                for (int i = 0; i < 16; i++) a[c][i] -= sv * vbuf[i * 64 + lane];
            }
        }
        __syncthreads();
    }

    // Phase 2: Q = H0 H1 ... H63 * [I64; 0]
    float qr[4][16];
#pragma unroll
    for (int c = 0; c < 4; c++)
#pragma unroll
        for (int i = 0; i < 16; i++) {
            int r = i * 64 + lane;
            qr[c][i] = (r == 4 * w + c) ? 1.f : 0.f;
        }
    for (int d = 63; d >= 0; d--) {
        const int wd = d >> 2, cd = d & 3;
        if (w == wd) {
#pragma unroll
            for (int c = 0; c < 4; c++) if (c == cd) {
#pragma unroll
                for (int i = 0; i < 16; i++) {
                    int r = i * 64 + lane;
                    vbuf[r] = (r < d) ? 0.f : a[c][i];
                }
            }
        }
        __syncthreads();
        float t2 = taub[d];
#pragma unroll
        for (int c = 0; c < 4; c++) {
            int j = 4 * w + c;
            if (j >= d) {
                float part = 0.f;
#pragma unroll
                for (int i = 0; i < 16; i++) part += vbuf[i * 64 + lane] * qr[c][i];
#pragma unroll
                for (int m = 1; m < 64; m <<= 1) part += __shfl_xor(part, m, 64);
                float sv = t2 * part;
#pragma unroll
                for (int i = 0; i < 16; i++) qr[c][i] -= sv * vbuf[i * 64 + lane];
            }
        }
        __syncthreads();
    }
#pragma unroll
    for (int c = 0; c < 4; c++)
#pragma unroll
        for (int i = 0; i < 16; i++)
            dst[(i * 64 + lane) * 64 + 4 * w + c] = qr[c][i];
}

// ---------------- K3: fused scores -> conv1x1 -> BN -> online softmax -> PV ----------------
// Block: 512 thr, tile = 16 q-rows x 32 m-cols, grid (64 n-tiles, 4 batches).
#define NT 16
#define MT 32
__global__ __launch_bounds__(512) void attn_fused(
    const float* __restrict__ q, const float* __restrict__ k, const float* __restrict__ v,
    const float* __restrict__ qgr, const float* __restrict__ kgr,
    const float* __restrict__ qn2, const float* __restrict__ kn2,
    const float* __restrict__ conv_w, const float* __restrict__ conv_b,
    const float* __restrict__ bn_gamma, const float* __restrict__ bn_beta,
    const float* __restrict__ bn_mean, const float* __restrict__ bn_var,
    const float* __restrict__ scale_p, const float* __restrict__ riem_p,
    const float* __restrict__ grass_p, float* __restrict__ out)
{
    extern __shared__ float smem[];
    float* qs   = smem;                    // [12][16][68]
    float* qgs  = qs   + 12 * 16 * 68;     // [12][16][68]
    float* ks   = qgs  + 12 * 16 * 68;     // [32][68]  (reused for v in PV)
    float* kgs  = ks   + 32 * 68;          // [32][68]
    float* ps   = kgs  + 32 * 68;          // [12][16][33]
    float* kn2s = ps   + 12 * 16 * 33;     // [12][32]
    float* qn2s = kn2s + 12 * 32;          // [12][16]
    float* wco  = qn2s + 12 * 16;          // [12][36]
    float* Abn  = wco  + 12 * 36;          // [12]
    float* Bbn  = Abn  + 12;               // [12]
    float* corr = Bbn  + 12;               // [12][16]

    const int tid = threadIdx.x;
    const int b = blockIdx.y;
    const int n0 = blockIdx.x * NT;
    const float scale = scale_p[0], riem_scale = riem_p[0], grass_scale = grass_p[0];

    for (int idx = tid; idx < 12 * 16 * 64; idx += 512) {
        int h = idx >> 10; int rem = idx & 1023; int n = rem >> 6; int d = rem & 63;
        size_t g = ((size_t)(b * 12 + h) << 16) + ((size_t)(n0 + n) << 6) + d;
        qs[(h * 16 + n) * 68 + d]  = q[g];
        qgs[(h * 16 + n) * 68 + d] = qgr[g];
    }
    if (tid < 192) { int h = tid >> 4, n = tid & 15; qn2s[tid] = qn2[(b * 12 + h) * 1024 + n0 + n]; }
    if (tid < 432) wco[tid] = conv_w[tid];
    if (tid >= 448 && tid < 460) {
        int o = tid - 448;
        float inv = bn_gamma[o] * rsqrtf(bn_var[o] + 1e-5f);
        Abn[o] = inv;
        Bbn[o] = (conv_b[o] - bn_mean[o]) * inv + bn_beta[o];
    }

    const int n_s = tid >> 5;   // 0..15 (q-row)
    const int mm_s = tid & 31;  // 0..31 (m within tile)  / PV: d-group

    float m_run[12], l_run[12], acc0[12], acc1[12];
#pragma unroll
    for (int o = 0; o < 12; o++) { m_run[o] = -1e30f; l_run[o] = 0.f; acc0[o] = 0.f; acc1[o] = 0.f; }

    const int lmm = tid >> 4;          // staging: 0..31
    const int ld4 = (tid & 15) * 4;    // staging: 0..60

    for (int m0 = 0; m0 < 1024; m0 += MT) {
        float y[12];
#pragma unroll
        for (int o = 0; o < 12; o++) y[o] = 0.f;

        for (int h = 0; h < 12; h++) {
            __syncthreads();
            {
                size_t g = ((size_t)(b * 12 + h) << 16) + ((size_t)(m0 + lmm) << 6) + ld4;
                *(float4*)&ks[lmm * 68 + ld4]  = *(const float4*)&k[g];
                *(float4*)&kgs[lmm * 68 + ld4] = *(const float4*)&kgr[g];
                if (h == 0 && tid < 384) {
                    int hh = tid >> 5, m2 = tid & 31;
                    kn2s[tid] = kn2[(b * 12 + hh) * 1024 + m0 + m2];
                }
            }
            __syncthreads();
            const float4* qrow  = (const float4*)&qs[(h * 16 + n_s) * 68];
            const float4* qgrow = (const float4*)&qgs[(h * 16 + n_s) * 68];
            const float4* krow  = (const float4*)&ks[mm_s * 68];
            const float4* kgrow = (const float4*)&kgs[mm_s * 68];
            float qk = 0.f, gr = 0.f;
#pragma unroll
            for (int kk = 0; kk < 16; kk++) {
                float4 aq = qrow[kk],  bk = krow[kk];
                qk += aq.x * bk.x + aq.y * bk.y + aq.z * bk.z + aq.w * bk.w;
                float4 ag = qgrow[kk], bg = kgrow[kk];
                gr += ag.x * bg.x + ag.y * bg.y + ag.z * bg.z + ag.w * bg.w;
            }
            float qn2v = qn2s[h * 16 + n_s];
            float kn2v = kn2s[h * 32 + mm_s];
            float att = qk * scale;
            float d2 = qn2v * qn2v + kn2v * kn2v - 2.f * qk * qk;
            float rie = -sqrtf(fmaxf(d2, 0.f) + 1e-8f) * riem_scale;
            float gra = gr * gr * grass_scale;
#pragma unroll
            for (int o = 0; o < 12; o++)
                y[o] += wco[o * 36 + h] * att + wco[o * 36 + 12 + h] * rie + wco[o * 36 + 24 + h] * gra;
        }

        // BN + online softmax (rows = 32 consecutive lanes share a q-row)
#pragma unroll
        for (int o = 0; o < 12; o++) {
            float yv = y[o] * Abn[o] + Bbn[o];
            float tmax = yv;
#pragma unroll
            for (int m = 1; m < 32; m <<= 1) tmax = fmaxf(tmax, __shfl_xor(tmax, m, 64));
            float mnew = fmaxf(m_run[o], tmax);
            float co = expf(m_run[o] - mnew);
            float p = expf(yv - mnew);
            float psum = p;
#pragma unroll
            for (int m = 1; m < 32; m <<= 1) psum += __shfl_xor(psum, m, 64);
            l_run[o] = l_run[o] * co + psum;
            m_run[o] = mnew;
            ps[(o * 16 + n_s) * 33 + mm_s] = p;
            if (mm_s == 0) corr[o * 16 + n_s] = co;
        }
        __syncthreads();

        // PV: thread (n_s, dg=mm_s) owns d = 2*dg, 2*dg+1 for all 12 heads
        for (int o = 0; o < 12; o++) {
            {
                size_t g = ((size_t)(b * 12 + o) << 16) + ((size_t)(m0 + lmm) << 6) + ld4;
                *(float4*)&ks[lmm * 68 + ld4] = *(const float4*)&v[g];
            }
            __syncthreads();
            float co = corr[o * 16 + n_s];
            float a0 = acc0[o] * co, a1 = acc1[o] * co;
            const float* prow = &ps[(o * 16 + n_s) * 33];
#pragma unroll
            for (int mm = 0; mm < 32; mm++) {
                float p = prow[mm];
                float2 vv = *(const float2*)&ks[mm * 68 + mm_s * 2];
                a0 += p * vv.x; a1 += p * vv.y;
            }
            acc0[o] = a0; acc1[o] = a1;
            __syncthreads();
        }
    }

    // finalize: broadcast l via LDS, write out [b][n][o*64+d]
    if (mm_s == 0) {
#pragma unroll
        for (int o = 0; o < 12; o++) corr[o * 16 + n_s] = l_run[o];
    }
    __syncthreads();
#pragma unroll
    for (int o = 0; o < 12; o++) {
        float invl = 1.f / corr[o * 16 + n_s];
        size_t g = ((size_t)(b * 1024 + n0 + n_s)) * 768 + o * 64 + mm_s * 2;
        out[g]     = acc0[o] * invl;
        out[g + 1] = acc1[o] * invl;
    }
}

// ---------------- K4: out = attno @ proj_w^T + proj_b ----------------
__global__ __launch_bounds__(256) void proj_gemm(
    const float* __restrict__ x, const float* __restrict__ w, const float* __restrict__ bias,
    float* __restrict__ out)
{
    __shared__ float As[16][68];
    __shared__ float Ws[16][68];
    const int tid = threadIdx.x;
    const int m0 = blockIdx.x * 64;
    const int c0 = blockIdx.y * 64;
    const int ty = tid >> 4, tx = tid & 15;
    const int lm = tid >> 2;
    const int lk = (tid & 3) * 4;
    float acc[4][4];
#pragma unroll
    for (int i = 0; i < 4; i++)
#pragma unroll
        for (int j = 0; j < 4; j++) acc[i][j] = 0.f;

    for (int kk0 = 0; kk0 < 768; kk0 += 16) {
        float4 av = *(const float4*)&x[(m0 + lm) * 768 + kk0 + lk];
        float4 wv = *(const float4*)&w[(c0 + lm) * 768 + kk0 + lk];
        __syncthreads();
        As[lk + 0][lm] = av.x; As[lk + 1][lm] = av.y; As[lk + 2][lm] = av.z; As[lk + 3][lm] = av.w;
        Ws[lk + 0][lm] = wv.x; Ws[lk + 1][lm] = wv.y; Ws[lk + 2][lm] = wv.z; Ws[lk + 3][lm] = wv.w;
        __syncthreads();
#pragma unroll
        for (int kk = 0; kk < 16; kk++) {
            float4 a  = *(const float4*)&As[kk][ty * 4];
            float4 bv = *(const float4*)&Ws[kk][tx * 4];
            acc[0][0] += a.x * bv.x; acc[0][1] += a.x * bv.y; acc[0][2] += a.x * bv.z; acc[0][3] += a.x * bv.w;
            acc[1][0] += a.y * bv.x; acc[1][1] += a.y * bv.y; acc[1][2] += a.y * bv.z; acc[1][3] += a.y * bv.w;
            acc[2][0] += a.z * bv.x; acc[2][1] += a.z * bv.y; acc[2][2] += a.z * bv.z; acc[2][3] += a.z * bv.w;
            acc[3][0] += a.w * bv.x; acc[3][1] += a.w * bv.y; acc[3][2] += a.w * bv.z; acc[3][3] += a.w * bv.w;
        }
    }
#pragma unroll
    for (int i = 0; i < 4; i++) {
        int row = m0 + ty * 4 + i;
#pragma unroll
        for (int j = 0; j < 4; j++) {
            int col = c0 + tx * 4 + j;
            out[(size_t)row * 768 + col] = acc[i][j] + bias[col];
        }
    }
}

extern "C" void kernel_launch(void* const* d_in, const int* in_sizes, int n_in,
                              void* d_out, int out_size, void* d_ws, size_t ws_size,
                              hipStream_t stream) {
    const float* x          = (const float*)d_in[0];
    const float* qkv_w      = (const float*)d_in[1];
    const float* qkv_b      = (const float*)d_in[2];
    const float* proj_w     = (const float*)d_in[3];
    const float* proj_b     = (const float*)d_in[4];
    const float* scale      = (const float*)d_in[5];
    const float* riem_scale = (const float*)d_in[6];
    const float* grass_scale= (const float*)d_in[7];
    const float* conv_w     = (const float*)d_in[8];
    const float* conv_b     = (const float*)d_in[9];
    const float* bn_gamma   = (const float*)d_in[10];
    const float* bn_beta    = (const float*)d_in[11];
    const float* bn_mean    = (const float*)d_in[12];
    const float* bn_var     = (const float*)d_in[13];
    float* out = (float*)d_out;

    float* q    = (float*)d_ws;
    float* k    = q    + 3145728;
    float* v    = k    + 3145728;
    float* qgr  = v    + 3145728;
    float* kgr  = qgr  + 3145728;
    float* qn2  = kgr  + 3145728;
    float* kn2  = qn2  + 49152;
    float* attno= kn2  + 49152;   // [4096][768]

    hipLaunchKernelGGL(qkv_gemm, dim3(64, 36), dim3(256), 0, stream, x, qkv_w, qkv_b, q, k, v);
    hipLaunchKernelGGL(row_norms, dim3(24576), dim3(256), 0, stream, q, k, qn2, kn2);
    hipLaunchKernelGGL(qr_kernel, dim3(96), dim3(1024), 0, stream, q, k, qgr, kgr);

    const int smem_bytes = (12*16*68*2 + 32*68*2 + 12*16*33 + 12*32 + 12*16 + 12*36 + 12 + 12 + 12*16) * 4;
    hipFuncSetAttribute(reinterpret_cast<const void*>(attn_fused),
                        hipFuncAttributeMaxDynamicSharedMemorySize, 160 * 1024);
    hipLaunchKernelGGL(attn_fused, dim3(64, 4), dim3(512), smem_bytes, stream,
                       q, k, v, qgr, kgr, qn2, kn2, conv_w, conv_b,
                       bn_gamma, bn_beta, bn_mean, bn_var,
                       scale, riem_scale, grass_scale, attno);
    hipLaunchKernelGGL(proj_gemm, dim3(64, 12), dim3(256), 0, stream, attno, proj_w, proj_b, out);
}

// Round 2
// 1530.274 us; speedup vs baseline: 1.4164x; 1.4164x over previous
//
#include <hip/hip_runtime.h>
#include <math.h>

// B=4, N=1024, C=768, H=12, D=64
// ws (floats): q[3145728] k[3145728] qpk kpk vpk (u32 views) qgrh kgrh (ushort) qn4 kn4
// attno aliases q (q f32 dead after qr/row_norms).

typedef __attribute__((ext_vector_type(8))) short short8;
typedef __attribute__((ext_vector_type(4))) float f32x4;

__device__ __forceinline__ unsigned bf16r(float x) {
    unsigned u = __float_as_uint(x);
    return (u + 0x7FFFu + ((u >> 16) & 1u)) >> 16;
}
__device__ __forceinline__ unsigned packhl(float x) {
    unsigned u = __float_as_uint(x);
    unsigned hi = (u + 0x7FFFu + ((u >> 16) & 1u)) & 0xFFFF0000u;
    float lo = x - __uint_as_float(hi);
    unsigned ul = __float_as_uint(lo);
    unsigned l16 = (ul + 0x7FFFu + ((ul >> 16) & 1u)) >> 16;
    return hi | (l16 & 0xFFFFu);
}
union U4S8 { uint4 u; short8 s; };
__device__ __forceinline__ short8 mk_hi(uint4 a, uint4 b) {
    U4S8 r;
    r.u.x = __builtin_amdgcn_perm(a.y, a.x, 0x07060302);
    r.u.y = __builtin_amdgcn_perm(a.w, a.z, 0x07060302);
    r.u.z = __builtin_amdgcn_perm(b.y, b.x, 0x07060302);
    r.u.w = __builtin_amdgcn_perm(b.w, b.z, 0x07060302);
    return r.s;
}
__device__ __forceinline__ short8 mk_lo(uint4 a, uint4 b) {
    U4S8 r;
    r.u.x = __builtin_amdgcn_perm(a.y, a.x, 0x05040100);
    r.u.y = __builtin_amdgcn_perm(a.w, a.z, 0x05040100);
    r.u.z = __builtin_amdgcn_perm(b.y, b.x, 0x05040100);
    r.u.w = __builtin_amdgcn_perm(b.w, b.z, 0x05040100);
    return r.s;
}
#define MFMA(a,b,c) __builtin_amdgcn_mfma_f32_16x16x32_bf16(a, b, c, 0, 0, 0)

// ---------------- K1: qkv GEMM + scatter (f32 + packed hi/lo bf16) ----------------
__global__ __launch_bounds__(256) void qkv_gemm(
    const float* __restrict__ x, const float* __restrict__ w, const float* __restrict__ bias,
    float* __restrict__ q, float* __restrict__ k,
    unsigned* __restrict__ qpk, unsigned* __restrict__ kpk, unsigned* __restrict__ vpk)
{
    __shared__ float As[16][68];
    __shared__ float Ws[16][68];
    const int tid = threadIdx.x;
    const int m0 = blockIdx.x * 64;
    const int c0 = blockIdx.y * 64;
    const int ty = tid >> 4, tx = tid & 15;
    const int lm = tid >> 2;
    const int lk = (tid & 3) * 4;
    float acc[4][4];
#pragma unroll
    for (int i = 0; i < 4; i++)
#pragma unroll
        for (int j = 0; j < 4; j++) acc[i][j] = 0.f;

    for (int kk0 = 0; kk0 < 768; kk0 += 16) {
        float4 av = *(const float4*)&x[(m0 + lm) * 768 + kk0 + lk];
        float4 wv = *(const float4*)&w[(c0 + lm) * 768 + kk0 + lk];
        __syncthreads();
        As[lk + 0][lm] = av.x; As[lk + 1][lm] = av.y; As[lk + 2][lm] = av.z; As[lk + 3][lm] = av.w;
        Ws[lk + 0][lm] = wv.x; Ws[lk + 1][lm] = wv.y; Ws[lk + 2][lm] = wv.z; Ws[lk + 3][lm] = wv.w;
        __syncthreads();
#pragma unroll
        for (int kk = 0; kk < 16; kk++) {
            float4 a  = *(const float4*)&As[kk][ty * 4];
            float4 bv = *(const float4*)&Ws[kk][tx * 4];
            acc[0][0] += a.x * bv.x; acc[0][1] += a.x * bv.y; acc[0][2] += a.x * bv.z; acc[0][3] += a.x * bv.w;
            acc[1][0] += a.y * bv.x; acc[1][1] += a.y * bv.y; acc[1][2] += a.y * bv.z; acc[1][3] += a.y * bv.w;
            acc[2][0] += a.z * bv.x; acc[2][1] += a.z * bv.y; acc[2][2] += a.z * bv.z; acc[2][3] += a.z * bv.w;
            acc[3][0] += a.w * bv.x; acc[3][1] += a.w * bv.y; acc[3][2] += a.w * bv.z; acc[3][3] += a.w * bv.w;
        }
    }
#pragma unroll
    for (int i = 0; i < 4; i++) {
        int row = m0 + ty * 4 + i;
        int bb = row >> 10, n = row & 1023;
#pragma unroll
        for (int j = 0; j < 4; j++) {
            int col = c0 + tx * 4 + j;
            float val = acc[i][j] + bias[col];
            int s = (col >= 1536) ? 2 : ((col >= 768) ? 1 : 0);
            int hc = col - s * 768;
            size_t idx = ((size_t)(bb * 12 + (hc >> 6)) << 16) + ((size_t)n << 6) + (hc & 63);
            if (s == 0)      { q[idx] = val; qpk[idx] = packhl(val); }
            else if (s == 1) { k[idx] = val; kpk[idx] = packhl(val); }
            else             { vpk[idx] = packhl(val); }
        }
    }
}

// ---------------- K1b: squared row norms (qn2^2, kn2^2) ----------------
__global__ __launch_bounds__(256) void row_norms(
    const float* __restrict__ q, const float* __restrict__ k,
    float* __restrict__ qn4, float* __restrict__ kn4)
{
    int wid = blockIdx.x * 4 + (threadIdx.x >> 6);
    int lane = threadIdx.x & 63;
    const float* src; float* dst; int r;
    if (wid < 49152) { src = q; dst = qn4; r = wid; }
    else             { src = k; dst = kn4; r = wid - 49152; }
    float xv = src[(size_t)r * 64 + lane];
    float s = xv * xv;
#pragma unroll
    for (int m = 1; m < 64; m <<= 1) s += __shfl_xor(s, m, 64);
    if (lane == 0) dst[r] = s * s;
}

// ---------------- K2: Householder QR (LAPACK signs), bf16 output ----------------
__global__ __launch_bounds__(1024) void qr_kernel(
    const float* __restrict__ q, const float* __restrict__ k,
    unsigned short* __restrict__ qgrh, unsigned short* __restrict__ kgrh)
{
    const int id = blockIdx.x;
    const float* src = (id & 1) ? k : q;
    unsigned short* dst = (id & 1) ? kgrh : qgrh;
    const int bh = id >> 1;
    src += (size_t)bh << 16;
    dst += (size_t)bh << 16;
    const int lane = threadIdx.x & 63;
    const int w = threadIdx.x >> 6;
    __shared__ float vbuf[1024];
    __shared__ float taub[64];

    float a[4][16];
#pragma unroll
    for (int c = 0; c < 4; c++)
#pragma unroll
        for (int i = 0; i < 16; i++)
            a[c][i] = src[(i * 64 + lane) * 64 + 4 * w + c];

    for (int d = 0; d < 64; d++) {
        const int wd = d >> 2, cd = d & 3;
        if (w == wd) {
#pragma unroll
            for (int c = 0; c < 4; c++) if (c == cd) {
                float part = 0.f;
#pragma unroll
                for (int i = 0; i < 16; i++) {
                    int r = i * 64 + lane; float xx = a[c][i];
                    part += (r >= d) ? xx * xx : 0.f;
                }
#pragma unroll
                for (int m = 1; m < 64; m <<= 1) part += __shfl_xor(part, m, 64);
                float sigma = part;
                float xd = __shfl(a[c][0], d, 64);
                float nrm = sqrtf(sigma);
                float beta = (xd >= 0.f) ? -nrm : nrm;
                float vd = xd - beta;
                float vtv = (sigma - xd * xd) + vd * vd;
                float tau2 = (vtv > 0.f) ? 2.f / vtv : 0.f;
                if (lane == d) a[c][0] = vd;
#pragma unroll
                for (int i = 0; i < 16; i++) {
                    int r = i * 64 + lane;
                    vbuf[r] = (r < d) ? 0.f : a[c][i];
                }
                if (lane == 0) taub[d] = tau2;
            }
        }
        __syncthreads();
        float t2 = taub[d];
#pragma unroll
        for (int c = 0; c < 4; c++) {
            int j = 4 * w + c;
            if (j > d) {
                float part = 0.f;
#pragma unroll
                for (int i = 0; i < 16; i++) part += vbuf[i * 64 + lane] * a[c][i];
#pragma unroll
                for (int m = 1; m < 64; m <<= 1) part += __shfl_xor(part, m, 64);
                float sv = t2 * part;
#pragma unroll
                for (int i = 0; i < 16; i++) a[c][i] -= sv * vbuf[i * 64 + lane];
            }
        }
        __syncthreads();
    }

    float qr[4][16];
#pragma unroll
    for (int c = 0; c < 4; c++)
#pragma unroll
        for (int i = 0; i < 16; i++) {
            int r = i * 64 + lane;
            qr[c][i] = (r == 4 * w + c) ? 1.f : 0.f;
        }
    for (int d = 63; d >= 0; d--) {
        const int wd = d >> 2, cd = d & 3;
        if (w == wd) {
#pragma unroll
            for (int c = 0; c < 4; c++) if (c == cd) {
#pragma unroll
                for (int i = 0; i < 16; i++) {
                    int r = i * 64 + lane;
                    vbuf[r] = (r < d) ? 0.f : a[c][i];
                }
            }
        }
        __syncthreads();
        float t2 = taub[d];
#pragma unroll
        for (int c = 0; c < 4; c++) {
            int j = 4 * w + c;
            if (j >= d) {
                float part = 0.f;
#pragma unroll
                for (int i = 0; i < 16; i++) part += vbuf[i * 64 + lane] * qr[c][i];
#pragma unroll
                for (int m = 1; m < 64; m <<= 1) part += __shfl_xor(part, m, 64);
                float sv = t2 * part;
#pragma unroll
                for (int i = 0; i < 16; i++) qr[c][i] -= sv * vbuf[i * 64 + lane];
            }
        }
        __syncthreads();
    }
#pragma unroll
    for (int c = 0; c < 4; c++)
#pragma unroll
        for (int i = 0; i < 16; i++)
            dst[(i * 64 + lane) * 64 + 4 * w + c] = (unsigned short)bf16r(qr[c][i]);
}

// ---------------- K3: fused MFMA scores -> conv -> BN -> online softmax -> PV ----------------
// 512 thr = 8 waves; NT=16 q-rows, MT=128 m-cols per step; all 12 heads.
// LDS byte map (dynamic, 158816 B):
//   0      qs   [12][16][64] u32 (q packed, chunk^row&7 swizzle)
//   49152  qgs  [12][16][64] ushort (qgr bf16)
//   73728  kL   [128][64] u32  | overlay: P [12][16][128] ushort (49152 B)
//   106496 kgrL [128][64] ushort
//   122880 vt   [64][128] u32 (V^T, chunk^(d&15)) | overlay: red [192][8] f32 | merge [16][64] f32
//   155648 Abn[12] Bbn[12] qn4s[192] mrun[192] lrun[192] coS[192]
#define SM_BYTES 158816
__global__ __launch_bounds__(512, 2) void attn_fused(
    const unsigned* __restrict__ qpk, const unsigned* __restrict__ kpk, const unsigned* __restrict__ vpk,
    const unsigned short* __restrict__ qgrh, const unsigned short* __restrict__ kgrh,
    const float* __restrict__ qn4g, const float* __restrict__ kn4g,
    const float* __restrict__ cw, const float* __restrict__ conv_b,
    const float* __restrict__ bn_gamma, const float* __restrict__ bn_beta,
    const float* __restrict__ bn_mean, const float* __restrict__ bn_var,
    const float* __restrict__ scale_p, const float* __restrict__ riem_p,
    const float* __restrict__ grass_p, float* __restrict__ attno)
{
    extern __shared__ char smem[];
    unsigned* qs   = (unsigned*)(smem);
    unsigned short* qgs  = (unsigned short*)(smem + 49152);
    unsigned* kL   = (unsigned*)(smem + 73728);
    unsigned short* kgrL = (unsigned short*)(smem + 106496);
    unsigned short* P_s  = (unsigned short*)(smem + 73728);
    unsigned* vt_s = (unsigned*)(smem + 122880);
    float* red     = (float*)(smem + 122880);
    float* mb      = (float*)(smem + 122880);
    float* Abn_s   = (float*)(smem + 155648);
    float* Bbn_s   = Abn_s + 12;
    float* qn4s    = Bbn_s + 12;
    float* mrun_s  = qn4s + 192;
    float* lrun_s  = mrun_s + 192;
    float* coS_s   = lrun_s + 192;

    const int tid = threadIdx.x;
    const int lane = tid & 63;
    const int w = tid >> 6;
    const int rowL = lane & 15;
    const int g = lane >> 4;
    const int r7 = rowL & 7;
    const int b = blockIdx.y;
    const int n0 = blockIdx.x * 16;
    const float scale = scale_p[0], riem_scale = riem_p[0], grass_scale = grass_p[0];

    if (tid >= 192 && tid < 204) {
        int o = tid - 192;
        float inv = bn_gamma[o] * rsqrtf(bn_var[o] + 1e-5f);
        Abn_s[o] = inv;
        Bbn_s[o] = fmaf(conv_b[o] - bn_mean[o], inv, bn_beta[o]);
    }
    if (tid < 192) {
        mrun_s[tid] = -1e30f; lrun_s[tid] = 0.f;
        qn4s[tid] = qn4g[(size_t)(b * 12 + (tid >> 4)) * 1024 + n0 + (tid & 15)];
    }
    // stage q packed + qgr (once)
#pragma unroll
    for (int e = 0; e < 6; e++) {
        int ci = tid + 512 * e;
        int R = ci >> 4, c = ci & 15;
        const unsigned* gp = qpk + ((size_t)(b * 12 + (R >> 4)) << 16) + (size_t)(n0 + (R & 15)) * 64 + c * 4;
        uint4 v = *(const uint4*)gp;
        *(uint4*)&qs[R * 64 + ((c ^ (R & 7)) << 2)] = v;
    }
#pragma unroll
    for (int e = 0; e < 3; e++) {
        int ci = tid + 512 * e;
        int R = ci >> 3, c = ci & 7;
        const unsigned short* gp = qgrh + ((size_t)(b * 12 + (R >> 4)) << 16) + (size_t)(n0 + (R & 15)) * 64 + c * 8;
        uint4 v = *(const uint4*)gp;
        *(uint4*)&qgs[R * 64 + ((c ^ (R & 7)) << 3)] = v;
    }

    f32x4 y[12], acc[12];
#pragma unroll
    for (int o = 0; o < 12; o++) { y[o] = (f32x4){0,0,0,0}; acc[o] = (f32x4){0,0,0,0}; }

    uint4 kreg[4], kgreg[2], vreg[4];
    // preload k tile (m0=0, h=0)
    {
        const unsigned* kp = kpk + ((size_t)(b * 12) << 16);
        const unsigned short* kg = kgrh + ((size_t)(b * 12) << 16);
#pragma unroll
        for (int e = 0; e < 4; e++) { int ci = tid + 512 * e; kreg[e] = *(const uint4*)&kp[(size_t)(ci >> 4) * 64 + (ci & 15) * 4]; }
#pragma unroll
        for (int e = 0; e < 2; e++) { int ci = tid + 512 * e; kgreg[e] = *(const uint4*)&kg[(size_t)(ci >> 3) * 64 + (ci & 7) * 8]; }
    }

    for (int m0 = 0; m0 < 1024; m0 += 128) {
        // ---------- scores over 12 heads ----------
        for (int h = 0; h < 12; h++) {
            // write k tile to LDS from regs
#pragma unroll
            for (int e = 0; e < 4; e++) {
                int ci = tid + 512 * e; int m = ci >> 4, c = ci & 15;
                *(uint4*)&kL[m * 64 + ((c ^ (m & 7)) << 2)] = kreg[e];
            }
#pragma unroll
            for (int e = 0; e < 2; e++) {
                int ci = tid + 512 * e; int m = ci >> 3, c = ci & 7;
                *(uint4*)&kgrL[m * 64 + ((c ^ (m & 7)) << 3)] = kgreg[e];
            }
            if (h < 11) {
                const unsigned* kp = kpk + ((size_t)(b * 12 + h + 1) << 16) + (size_t)m0 * 64;
                const unsigned short* kg = kgrh + ((size_t)(b * 12 + h + 1) << 16) + (size_t)m0 * 64;
#pragma unroll
                for (int e = 0; e < 4; e++) { int ci = tid + 512 * e; kreg[e] = *(const uint4*)&kp[(size_t)(ci >> 4) * 64 + (ci & 15) * 4]; }
#pragma unroll
                for (int e = 0; e < 2; e++) { int ci = tid + 512 * e; kgreg[e] = *(const uint4*)&kg[(size_t)(ci >> 3) * 64 + (ci & 7) * 8]; }
            }
            __syncthreads();

            float kn4v = kn4g[(size_t)(b * 12 + h) * 1024 + m0 + w * 16 + rowL];
            short8 qhiF[2], qloF[2], khiF[2], kloF[2], qgF[2], kgF[2];
#pragma unroll
            for (int ks = 0; ks < 2; ks++) {
                int c0 = ks * 8 + g * 2;
                const unsigned* qrow = &qs[(h * 16 + rowL) * 64];
                uint4 a0 = *(const uint4*)&qrow[((c0 ^ r7) << 2)];
                uint4 a1 = *(const uint4*)&qrow[(((c0 + 1) ^ r7) << 2)];
                qhiF[ks] = mk_hi(a0, a1); qloF[ks] = mk_lo(a0, a1);
                const unsigned* krow = &kL[(w * 16 + rowL) * 64];
                uint4 b0 = *(const uint4*)&krow[((c0 ^ r7) << 2)];
                uint4 b1 = *(const uint4*)&krow[(((c0 + 1) ^ r7) << 2)];
                khiF[ks] = mk_hi(b0, b1); kloF[ks] = mk_lo(b0, b1);
                int cg = ks * 4 + g;
                qgF[ks] = *(const short8*)&qgs[(h * 16 + rowL) * 64 + ((cg ^ r7) << 3)];
                kgF[ks] = *(const short8*)&kgrL[(w * 16 + rowL) * 64 + ((cg ^ r7) << 3)];
            }
            f32x4 s1 = {0,0,0,0}, s2 = {0,0,0,0};
#pragma unroll
            for (int ks = 0; ks < 2; ks++) {
                s1 = MFMA(qhiF[ks], khiF[ks], s1);
                s1 = MFMA(qhiF[ks], kloF[ks], s1);
                s1 = MFMA(qloF[ks], khiF[ks], s1);
                s2 = MFMA(qgF[ks], kgF[ks], s2);
            }
#pragma unroll
            for (int r = 0; r < 4; r++) {
                float qk = s1[r], gr = s2[r];
                float qn4v = qn4s[h * 16 + g * 4 + r];
                float att = qk * scale;
                float d2 = qn4v + kn4v - 2.f * qk * qk;
                float rie = -sqrtf(fmaxf(d2, 0.f) + 1e-8f) * riem_scale;
                float gra = gr * gr * grass_scale;
#pragma unroll
                for (int o = 0; o < 12; o++)
                    y[o][r] = fmaf(cw[o * 36 + h], att,
                               fmaf(cw[o * 36 + 12 + h], rie,
                                fmaf(cw[o * 36 + 24 + h], gra, y[o][r])));
            }
            __syncthreads();
        }

        // ---------- batched BN + online softmax ----------
        // issue v loads for o=0 (transposed-friendly pattern: d=tid&63, 4 m each)
        {
            const unsigned* vp = vpk + ((size_t)(b * 12) << 16) + (size_t)m0 * 64;
            int d = tid & 63;
#pragma unroll
            for (int e = 0; e < 4; e++) {
                int mbase = (tid >> 6) * 4 + 32 * e;
                vreg[e].x = vp[(size_t)(mbase + 0) * 64 + d];
                vreg[e].y = vp[(size_t)(mbase + 1) * 64 + d];
                vreg[e].z = vp[(size_t)(mbase + 2) * 64 + d];
                vreg[e].w = vp[(size_t)(mbase + 3) * 64 + d];
            }
        }
#pragma unroll
        for (int o = 0; o < 12; o++) {
#pragma unroll
            for (int r = 0; r < 4; r++) {
                float yv = fmaf(y[o][r], Abn_s[o], Bbn_s[o]);
                y[o][r] = yv;
                float mx = yv;
                mx = fmaxf(mx, __shfl_xor(mx, 1, 64));
                mx = fmaxf(mx, __shfl_xor(mx, 2, 64));
                mx = fmaxf(mx, __shfl_xor(mx, 4, 64));
                mx = fmaxf(mx, __shfl_xor(mx, 8, 64));
                if (rowL == 0) red[(o * 16 + g * 4 + r) * 8 + w] = mx;
            }
        }
        __syncthreads(); // B1
        if (tid < 192) {
            float m8 = red[tid * 8];
#pragma unroll
            for (int j = 1; j < 8; j++) m8 = fmaxf(m8, red[tid * 8 + j]);
            float mo = mrun_s[tid];
            float mn = fmaxf(mo, m8);
            mrun_s[tid] = mn;
            coS_s[tid] = expf(mo - mn);
        }
        __syncthreads(); // B2
#pragma unroll
        for (int o = 0; o < 12; o++) {
#pragma unroll
            for (int r = 0; r < 4; r++) {
                int row = g * 4 + r;
                float mn = mrun_s[o * 16 + row];
                float p = expf(y[o][r] - mn);
                unsigned us = bf16r(p);
                float pr = __uint_as_float(us << 16);
                int m = w * 16 + rowL;
                P_s[(o * 16 + row) * 128 + ((((m >> 3) ^ (row & 7))) << 3) + (m & 7)] = (unsigned short)us;
                float s = pr;
                s += __shfl_xor(s, 1, 64); s += __shfl_xor(s, 2, 64);
                s += __shfl_xor(s, 4, 64); s += __shfl_xor(s, 8, 64);
                if (rowL == 0) red[(o * 16 + row) * 8 + w] = s;
                y[o][r] = 0.f;
            }
        }
        __syncthreads(); // B3
        if (tid < 192) {
            float s8 = 0.f;
#pragma unroll
            for (int j = 0; j < 8; j++) s8 += red[tid * 8 + j];
            lrun_s[tid] = fmaf(lrun_s[tid], coS_s[tid], s8);
        }
        __syncthreads(); // B4

        // ---------- PV over 12 heads ----------
        const int km = w >> 2, wd = w & 3;
#pragma unroll
        for (int o = 0; o < 12; o++) {
            // write V^T tile from regs (swizzle chunk ^ (d&15))
            {
                int d = tid & 63;
#pragma unroll
                for (int e = 0; e < 4; e++) {
                    int mc = (tid >> 6) + 8 * e; // m>>2
                    *(uint4*)&vt_s[d * 128 + ((mc ^ (d & 15)) << 2)] = vreg[e];
                }
            }
            if (o < 11) {
                const unsigned* vp = vpk + ((size_t)(b * 12 + o + 1) << 16) + (size_t)m0 * 64;
                int d = tid & 63;
#pragma unroll
                for (int e = 0; e < 4; e++) {
                    int mbase = (tid >> 6) * 4 + 32 * e;
                    vreg[e].x = vp[(size_t)(mbase + 0) * 64 + d];
                    vreg[e].y = vp[(size_t)(mbase + 1) * 64 + d];
                    vreg[e].z = vp[(size_t)(mbase + 2) * 64 + d];
                    vreg[e].w = vp[(size_t)(mbase + 3) * 64 + d];
                }
            } else if (m0 + 128 < 1024) {
                const unsigned* kp = kpk + ((size_t)(b * 12) << 16) + (size_t)(m0 + 128) * 64;
                const unsigned short* kg = kgrh + ((size_t)(b * 12) << 16) + (size_t)(m0 + 128) * 64;
#pragma unroll
                for (int e = 0; e < 4; e++) { int ci = tid + 512 * e; kreg[e] = *(const uint4*)&kp[(size_t)(ci >> 4) * 64 + (ci & 15) * 4]; }
#pragma unroll
                for (int e = 0; e < 2; e++) { int ci = tid + 512 * e; kgreg[e] = *(const uint4*)&kg[(size_t)(ci >> 3) * 64 + (ci & 7) * 8]; }
            }
            __syncthreads();
#pragma unroll
            for (int r = 0; r < 4; r++) acc[o][r] *= coS_s[o * 16 + g * 4 + r];
#pragma unroll
            for (int ks = 0; ks < 2; ks++) {
                int mc8 = km * 8 + ks * 4 + g;   // m>>3
                short8 pa = *(const short8*)&P_s[(o * 16 + rowL) * 128 + ((mc8 ^ r7) << 3)];
                int c0 = km * 16 + ks * 8 + g * 2; // m>>2
                const unsigned* vrow = &vt_s[(wd * 16 + rowL) * 128];
                uint4 b0 = *(const uint4*)&vrow[((c0 ^ rowL) << 2)];
                uint4 b1 = *(const uint4*)&vrow[(((c0 + 1) ^ rowL) << 2)];
                short8 vh = mk_hi(b0, b1), vl = mk_lo(b0, b1);
                acc[o] = MFMA(pa, vh, acc[o]);
                acc[o] = MFMA(pa, vl, acc[o]);
            }
            __syncthreads();
        }
    }

    // ---------- epilogue: merge km halves, normalize, store ----------
    const int km = w >> 2, wd = w & 3;
#pragma unroll
    for (int o = 0; o < 12; o++) {
        if (km == 1) {
#pragma unroll
            for (int r = 0; r < 4; r++) mb[(g * 4 + r) * 64 + wd * 16 + rowL] = acc[o][r];
        }
        __syncthreads();
        if (km == 0) {
#pragma unroll
            for (int r = 0; r < 4; r++) {
                int row = g * 4 + r;
                float tot = acc[o][r] + mb[row * 64 + wd * 16 + rowL];
                float inv = 1.f / lrun_s[o * 16 + row];
                attno[((size_t)(b * 1024 + n0 + row)) * 768 + o * 64 + wd * 16 + rowL] = tot * inv;
            }
        }
        __syncthreads();
    }
}

// ---------------- K4: out = attno @ proj_w^T + proj_b ----------------
__global__ __launch_bounds__(256) void proj_gemm(
    const float* __restrict__ x, const float* __restrict__ w, const float* __restrict__ bias,
    float* __restrict__ out)
{
    __shared__ float As[16][68];
    __shared__ float Ws[16][68];
    const int tid = threadIdx.x;
    const int m0 = blockIdx.x * 64;
    const int c0 = blockIdx.y * 64;
    const int ty = tid >> 4, tx = tid & 15;
    const int lm = tid >> 2;
    const int lk = (tid & 3) * 4;
    float acc[4][4];
#pragma unroll
    for (int i = 0; i < 4; i++)
#pragma unroll
        for (int j = 0; j < 4; j++) acc[i][j] = 0.f;

    for (int kk0 = 0; kk0 < 768; kk0 += 16) {
        float4 av = *(const float4*)&x[(m0 + lm) * 768 + kk0 + lk];
        float4 wv = *(const float4*)&w[(c0 + lm) * 768 + kk0 + lk];
        __syncthreads();
        As[lk + 0][lm] = av.x; As[lk + 1][lm] = av.y; As[lk + 2][lm] = av.z; As[lk + 3][lm] = av.w;
        Ws[lk + 0][lm] = wv.x; Ws[lk + 1][lm] = wv.y; Ws[lk + 2][lm] = wv.z; Ws[lk + 3][lm] = wv.w;
        __syncthreads();
#pragma unroll
        for (int kk = 0; kk < 16; kk++) {
            float4 a  = *(const float4*)&As[kk][ty * 4];
            float4 bv = *(const float4*)&Ws[kk][tx * 4];
            acc[0][0] += a.x * bv.x; acc[0][1] += a.x * bv.y; acc[0][2] += a.x * bv.z; acc[0][3] += a.x * bv.w;
            acc[1][0] += a.y * bv.x; acc[1][1] += a.y * bv.y; acc[1][2] += a.y * bv.z; acc[1][3] += a.y * bv.w;
            acc[2][0] += a.z * bv.x; acc[2][1] += a.z * bv.y; acc[2][2] += a.z * bv.z; acc[2][3] += a.z * bv.w;
            acc[3][0] += a.w * bv.x; acc[3][1] += a.w * bv.y; acc[3][2] += a.w * bv.z; acc[3][3] += a.w * bv.w;
        }
    }
#pragma unroll
    for (int i = 0; i < 4; i++) {
        int row = m0 + ty * 4 + i;
#pragma unroll
        for (int j = 0; j < 4; j++) {
            int col = c0 + tx * 4 + j;
            out[(size_t)row * 768 + col] = acc[i][j] + bias[col];
        }
    }
}

extern "C" void kernel_launch(void* const* d_in, const int* in_sizes, int n_in,
                              void* d_out, int out_size, void* d_ws, size_t ws_size,
                              hipStream_t stream) {
    const float* x          = (const float*)d_in[0];
    const float* qkv_w      = (const float*)d_in[1];
    const float* qkv_b      = (const float*)d_in[2];
    const float* proj_w     = (const float*)d_in[3];
    const float* proj_b     = (const float*)d_in[4];
    const float* scale      = (const float*)d_in[5];
    const float* riem_scale = (const float*)d_in[6];
    const float* grass_scale= (const float*)d_in[7];
    const float* conv_w     = (const float*)d_in[8];
    const float* conv_b     = (const float*)d_in[9];
    const float* bn_gamma   = (const float*)d_in[10];
    const float* bn_beta    = (const float*)d_in[11];
    const float* bn_mean    = (const float*)d_in[12];
    const float* bn_var     = (const float*)d_in[13];
    float* out = (float*)d_out;

    float* q   = (float*)d_ws;                 // 3145728 f32 ; later aliased as attno
    float* k   = q + 3145728;
    unsigned* qpk = (unsigned*)(k + 3145728);
    unsigned* kpk = qpk + 3145728;
    unsigned* vpk = kpk + 3145728;
    unsigned short* qgrh = (unsigned short*)(vpk + 3145728);
    unsigned short* kgrh = qgrh + 3145728;
    float* qn4 = (float*)(kgrh + 3145728);
    float* kn4 = qn4 + 49152;
    float* attno = q; // alias: q f32 dead after qr_kernel/row_norms

    hipLaunchKernelGGL(qkv_gemm, dim3(64, 36), dim3(256), 0, stream,
                       x, qkv_w, qkv_b, q, k, qpk, kpk, vpk);
    hipLaunchKernelGGL(row_norms, dim3(24576), dim3(256), 0, stream, q, k, qn4, kn4);
    hipLaunchKernelGGL(qr_kernel, dim3(96), dim3(1024), 0, stream, q, k, qgrh, kgrh);

    hipFuncSetAttribute(reinterpret_cast<const void*>(attn_fused),
                        hipFuncAttributeMaxDynamicSharedMemorySize, SM_BYTES);
    hipLaunchKernelGGL(attn_fused, dim3(64, 4), dim3(512), SM_BYTES, stream,
                       qpk, kpk, vpk, qgrh, kgrh, qn4, kn4, conv_w, conv_b,
                       bn_gamma, bn_beta, bn_mean, bn_var,
                       scale, riem_scale, grass_scale, attno);
    hipLaunchKernelGGL(proj_gemm, dim3(64, 12), dim3(256), 0, stream,
                       attno, proj_w, proj_b, out);
}